// Round 1
// baseline (894.050 us; speedup 1.0000x reference)
//
#include <hip/hip_runtime.h>
#include <hip/hip_bf16.h>

// EdgeModel: out = (softplus(softplus([src|dst|ea|u[batch]] @ W1 + b1) @ W2 + b2)) @ W3 + b3
// v2: 48KB LDS pool (h1/h2 share one buffer) -> 3 blocks/CU; register prefetch of
// next x-chunk across raw s_barriers (no vmcnt drain); native bf16 cvt (cvt_pk);
// setprio around MFMA clusters.

#define N_EDGE 400000
#define D_FEAT 128
#define D_HID  256
#define D_OUTW 128
#define M_TILE 64

using bf16   = __bf16;
using bf16x4 = __attribute__((ext_vector_type(4))) bf16;
using bf16x8 = __attribute__((ext_vector_type(8))) bf16;
using f32x4  = __attribute__((ext_vector_type(4))) float;

#define FENCE() asm volatile("" ::: "memory")
#define BARRIER() do { FENCE(); __builtin_amdgcn_s_barrier(); FENCE(); } while (0)
#define LGKM0_BARRIER() do { asm volatile("s_waitcnt lgkmcnt(0)" ::: "memory"); \
                             __builtin_amdgcn_s_barrier(); FENCE(); } while (0)

__device__ __forceinline__ unsigned short f2bf(float x) {
  unsigned u = __float_as_uint(x);
  unsigned r = u + 0x7FFFu + ((u >> 16) & 1u);   // RNE
  return (unsigned short)(r >> 16);
}

__device__ __forceinline__ float softplus_t(float x) {
  // torch Softplus(beta=1, threshold=20)
  float sp = __logf(1.0f + __expf(x));
  return x > 20.0f ? x : sp;
}

// ---- prep: W[K][N] f32 -> Wt[N][K] bf16 (so A-frags are 16B-contiguous) ----
__global__ void prep_weights(const float* __restrict__ W1,
                             const float* __restrict__ W2,
                             const float* __restrict__ W3,
                             short* __restrict__ wt) {
  __shared__ float tile[32][33];
  int b = blockIdx.x;
  const float* W; short* Wt; int K, N, kt, nt;
  if (b < 128)      { W = W1; Wt = wt;          K = 512; N = 256; kt = b & 15;  nt = b >> 4; }
  else if (b < 192) { int bb = b - 128; W = W2; Wt = wt + 131072; K = 256; N = 256; kt = bb & 7; nt = bb >> 3; }
  else              { int bb = b - 192; W = W3; Wt = wt + 196608; K = 256; N = 128; kt = bb & 7; nt = bb >> 3; }
  int tx = threadIdx.x, ty = threadIdx.y;
#pragma unroll
  for (int i = 0; i < 4; ++i) {
    int k = kt * 32 + ty + i * 8;
    tile[ty + i * 8][tx] = W[k * N + nt * 32 + tx];
  }
  __syncthreads();
#pragma unroll
  for (int i = 0; i < 4; ++i) {
    int n = nt * 32 + ty + i * 8;
    Wt[n * K + kt * 32 + tx] = (short)f2bf(tile[tx][ty + i * 8]);
  }
}

// LDS layout: element [m][k] of a row-length-256 buffer lives at
//   m*256 + ((k>>3) ^ (m&7))*8 + (k&7)   (elems; 16B-group xor swizzle)
// x-chunk uses row length 128: m*128 + ((k>>3) ^ (m&7))*8 + (k&7)

__global__ __launch_bounds__(256, 3) void edge_mlp(
    const float* __restrict__ src, const float* __restrict__ dst,
    const float* __restrict__ eattr, const float* __restrict__ u,
    const int* __restrict__ batch,
    const float* __restrict__ b1, const float* __restrict__ b2,
    const float* __restrict__ b3,
    const short* __restrict__ wt1, const short* __restrict__ wt2,
    const short* __restrict__ wt3,
    float* __restrict__ out) {
  __shared__ bf16 xs[M_TILE * 128];   // 16 KB: current 128-wide K chunk of x
  __shared__ bf16 hs[M_TILE * 256];   // 32 KB: h1, then (after barrier) h2

  const bf16* w1 = (const bf16*)wt1;
  const bf16* w2 = (const bf16*)wt2;
  const bf16* w3 = (const bf16*)wt3;

  const int tid  = threadIdx.x;
  const int wave = tid >> 6;
  const int lane = tid & 63;
  const int quad = lane >> 4;
  const int l16  = lane & 15;
  const int e0   = blockIdx.x * M_TILE;

  // staging role: thread -> (row sm, quarter sq)
  const int sm = tid >> 2;
  const int sq = tid & 3;
  const int sb = batch[e0 + sm];

  f32x4 acc[4][4];
#pragma unroll
  for (int i = 0; i < 4; ++i)
#pragma unroll
    for (int j = 0; j < 4; ++j) acc[i][j] = (f32x4)(0.0f);

  // ---------------- layer 1: K=512 in 4 chunks of 128 ----------------
  // prefetch chunk 0 into registers
  f32x4 pf[8];
  {
    const float* base = src + (size_t)(e0 + sm) * D_FEAT;
#pragma unroll
    for (int f = 0; f < 8; ++f) pf[f] = *(const f32x4*)(base + 4 * (sq + 4 * f));
  }

#pragma unroll
  for (int c = 0; c < 4; ++c) {
    // convert current chunk (waits on pf loads), freeing pf for the next prefetch
    bf16x4 pk[8];
#pragma unroll
    for (int f = 0; f < 8; ++f) {
      pk[f][0] = (bf16)pf[f][0]; pk[f][1] = (bf16)pf[f][1];
      pk[f][2] = (bf16)pf[f][2]; pk[f][3] = (bf16)pf[f][3];
    }
    // issue next chunk's global loads; they stay in flight across the barriers
    if (c < 3) {
      const float* base;
      if (c == 0)      base = dst   + (size_t)(e0 + sm) * D_FEAT;
      else if (c == 1) base = eattr + (size_t)(e0 + sm) * D_FEAT;
      else             base = u     + (size_t)sb * D_FEAT;
#pragma unroll
      for (int f = 0; f < 8; ++f) pf[f] = *(const f32x4*)(base + 4 * (sq + 4 * f));
    }
    BARRIER();                        // all waves done reading xs (chunk c-1)
#pragma unroll
    for (int f = 0; f < 8; ++f) {
      int col = 4 * (sq + 4 * f);
      int g   = col >> 3;
      int off = sm * 128 + (((g ^ (sm & 7)) << 3) + (col & 7));
      *(bf16x4*)&xs[off] = pk[f];
    }
    LGKM0_BARRIER();                  // xs writes visible to the block

    __builtin_amdgcn_s_setprio(1);
#pragma unroll
    for (int ks = 0; ks < 4; ++ks) {
      int kg = c * 128 + ks * 32 + quad * 8;
      bf16x8 a[4], bfr[4];
#pragma unroll
      for (int i = 0; i < 4; ++i)
        a[i] = *(const bf16x8*)(w1 + (wave * 64 + i * 16 + l16) * 512 + kg);
#pragma unroll
      for (int j = 0; j < 4; ++j) {
        int m = j * 16 + l16;
        int g = ks * 4 + quad;
        bfr[j] = *(const bf16x8*)&xs[m * 128 + ((g ^ (m & 7)) << 3)];
      }
#pragma unroll
      for (int i = 0; i < 4; ++i)
#pragma unroll
        for (int j = 0; j < 4; ++j)
          acc[i][j] = __builtin_amdgcn_mfma_f32_16x16x32_bf16(a[i], bfr[j], acc[i][j], 0, 0, 0);
    }
    __builtin_amdgcn_s_setprio(0);
  }

  // epilogue 1: h1 = softplus(acc + b1) -> hs  (hs is fresh; no barrier needed first)
#pragma unroll
  for (int i = 0; i < 4; ++i) {
    int fbase = wave * 64 + i * 16 + quad * 4;
    f32x4 bias = *(const f32x4*)(b1 + fbase);
#pragma unroll
    for (int j = 0; j < 4; ++j) {
      int m = j * 16 + l16;
      bf16x4 p;
#pragma unroll
      for (int r = 0; r < 4; ++r) p[r] = (bf16)softplus_t(acc[i][j][r] + bias[r]);
      int g   = fbase >> 3;
      int off = m * 256 + (((g ^ (m & 7)) << 3) + (fbase & 7));
      *(bf16x4*)&hs[off] = p;
    }
  }
  LGKM0_BARRIER();                    // h1 visible

  // ---------------- layer 2: K=256 from hs (h1) ----------------
  f32x4 acc2[4][4];
#pragma unroll
  for (int i = 0; i < 4; ++i)
#pragma unroll
    for (int j = 0; j < 4; ++j) acc2[i][j] = (f32x4)(0.0f);

  __builtin_amdgcn_s_setprio(1);
#pragma unroll
  for (int ks = 0; ks < 8; ++ks) {
    int kg = ks * 32 + quad * 8;
    bf16x8 a[4], bfr[4];
#pragma unroll
    for (int i = 0; i < 4; ++i)
      a[i] = *(const bf16x8*)(w2 + (wave * 64 + i * 16 + l16) * 256 + kg);
#pragma unroll
    for (int j = 0; j < 4; ++j) {
      int m = j * 16 + l16;
      int g = ks * 4 + quad;
      bfr[j] = *(const bf16x8*)&hs[m * 256 + ((g ^ (m & 7)) << 3)];
    }
#pragma unroll
    for (int i = 0; i < 4; ++i)
#pragma unroll
      for (int j = 0; j < 4; ++j)
        acc2[i][j] = __builtin_amdgcn_mfma_f32_16x16x32_bf16(a[i], bfr[j], acc2[i][j], 0, 0, 0);
  }
  __builtin_amdgcn_s_setprio(0);
  BARRIER();                          // all waves done READING h1 -> hs reusable

  // epilogue 2: h2 = softplus(acc2 + b2) -> hs (overwrites h1)
#pragma unroll
  for (int i = 0; i < 4; ++i) {
    int fbase = wave * 64 + i * 16 + quad * 4;
    f32x4 bias = *(const f32x4*)(b2 + fbase);
#pragma unroll
    for (int j = 0; j < 4; ++j) {
      int m = j * 16 + l16;
      bf16x4 p;
#pragma unroll
      for (int r = 0; r < 4; ++r) p[r] = (bf16)softplus_t(acc2[i][j][r] + bias[r]);
      int g   = fbase >> 3;
      int off = m * 256 + (((g ^ (m & 7)) << 3) + (fbase & 7));
      *(bf16x4*)&hs[off] = p;
    }
  }
  LGKM0_BARRIER();                    // h2 visible

  // ---------------- layer 3: K=256 from hs (h2), f_out=128 ----------------
  const int f0 = (wave & 1) * 64;
  const int m0 = (wave >> 1) * 32;
  f32x4 acc3[4][2];
#pragma unroll
  for (int i = 0; i < 4; ++i)
#pragma unroll
    for (int j = 0; j < 2; ++j) acc3[i][j] = (f32x4)(0.0f);

  __builtin_amdgcn_s_setprio(1);
#pragma unroll
  for (int ks = 0; ks < 8; ++ks) {
    int kg = ks * 32 + quad * 8;
    bf16x8 a[4], bfr[2];
#pragma unroll
    for (int i = 0; i < 4; ++i)
      a[i] = *(const bf16x8*)(w3 + (f0 + i * 16 + l16) * 256 + kg);
#pragma unroll
    for (int j = 0; j < 2; ++j) {
      int m = m0 + j * 16 + l16;
      int g = ks * 4 + quad;
      bfr[j] = *(const bf16x8*)&hs[m * 256 + ((g ^ (m & 7)) << 3)];
    }
#pragma unroll
    for (int i = 0; i < 4; ++i)
#pragma unroll
      for (int j = 0; j < 2; ++j)
        acc3[i][j] = __builtin_amdgcn_mfma_f32_16x16x32_bf16(a[i], bfr[j], acc3[i][j], 0, 0, 0);
  }
  __builtin_amdgcn_s_setprio(0);

  // epilogue 3: out = acc3 + b3 ; lane stores float4 (4 consecutive f) per (i,j)
#pragma unroll
  for (int i = 0; i < 4; ++i) {
    int fbase = f0 + i * 16 + quad * 4;
    f32x4 bias = *(const f32x4*)(b3 + fbase);
#pragma unroll
    for (int j = 0; j < 2; ++j) {
      int m = m0 + j * 16 + l16;
      f32x4 v = acc3[i][j] + bias;
      *(f32x4*)(out + (size_t)(e0 + m) * D_OUTW + fbase) = v;
    }
  }
}

extern "C" void kernel_launch(void* const* d_in, const int* in_sizes, int n_in,
                              void* d_out, int out_size, void* d_ws, size_t ws_size,
                              hipStream_t stream) {
  const float* src   = (const float*)d_in[0];
  const float* dst   = (const float*)d_in[1];
  const float* eattr = (const float*)d_in[2];
  const float* u     = (const float*)d_in[3];
  const int*   batch = (const int*)d_in[4];
  const float* W1    = (const float*)d_in[5];
  const float* b1    = (const float*)d_in[6];
  const float* W2    = (const float*)d_in[7];
  const float* b2    = (const float*)d_in[8];
  const float* W3    = (const float*)d_in[9];
  const float* b3    = (const float*)d_in[10];
  float* out = (float*)d_out;
  short* wt  = (short*)d_ws;   // wt1 @0 (131072), wt2 @131072 (65536), wt3 @196608 (32768)

  prep_weights<<<224, dim3(32, 8), 0, stream>>>(W1, W2, W3, wt);
  edge_mlp<<<N_EDGE / M_TILE, 256, 0, stream>>>(src, dst, eattr, u, batch,
                                                b1, b2, b3,
                                                wt, wt + 131072, wt + 196608, out);
}